// Round 1
// baseline (665.233 us; speedup 1.0000x reference)
//
#include <hip/hip_runtime.h>

#define NUM_RELS 19

// ---------------- CSR build ----------------

__global__ void hist_kernel(const int* __restrict__ dst, int* __restrict__ count, int E) {
    int e = blockIdx.x * blockDim.x + threadIdx.x;
    if (e < E) atomicAdd(&count[dst[e]], 1);
}

// chunk = 2048 per block (256 threads x 8 items)
__global__ void scan1_kernel(const int* __restrict__ count, int* __restrict__ row_start,
                             int* __restrict__ bsum, int N) {
    __shared__ int lds[256];
    int t = threadIdx.x;
    int base = blockIdx.x * 2048 + t * 8;
    int v[8];
    int s = 0;
#pragma unroll
    for (int k = 0; k < 8; ++k) {
        v[k] = (base + k < N) ? count[base + k] : 0;
        s += v[k];
    }
    lds[t] = s;
    __syncthreads();
    // Hillis-Steele inclusive scan over 256 thread sums
    for (int off = 1; off < 256; off <<= 1) {
        int x = (t >= off) ? lds[t - off] : 0;
        __syncthreads();
        lds[t] += x;
        __syncthreads();
    }
    int run = lds[t] - s;  // exclusive prefix of this thread's chunk
#pragma unroll
    for (int k = 0; k < 8; ++k) {
        if (base + k < N) row_start[base + k] = run;
        run += v[k];
    }
    if (t == 255) bsum[blockIdx.x] = lds[255];
}

__global__ void scan2_kernel(int* __restrict__ bsum, int NB) {
    __shared__ int lds[256];
    int t = threadIdx.x;
    int v = (t < NB) ? bsum[t] : 0;
    lds[t] = v;
    __syncthreads();
    for (int off = 1; off < 256; off <<= 1) {
        int x = (t >= off) ? lds[t - off] : 0;
        __syncthreads();
        lds[t] += x;
        __syncthreads();
    }
    if (t < NB) bsum[t] = lds[t] - v;  // exclusive
}

__global__ void scan3_kernel(int* __restrict__ row_start, int* __restrict__ cursor,
                             const int* __restrict__ bsum, int N, int E) {
    int i = blockIdx.x * blockDim.x + threadIdx.x;
    if (i < N) {
        int v = row_start[i] + bsum[i >> 11];
        row_start[i] = v;
        cursor[i] = v;
    } else if (i == N) {
        row_start[N] = E;
    }
}

__global__ void scatter_kernel(const int* __restrict__ dst, int* __restrict__ cursor,
                               int* __restrict__ eid, int E) {
    int e = blockIdx.x * blockDim.x + threadIdx.x;
    if (e < E) {
        int p = atomicAdd(&cursor[dst[e]], 1);
        eid[p] = e;
    }
}

// ---------------- Layer 1: h1[v] = relu(sum_e W1row[etype[e]] + b1) ----------------

__global__ __launch_bounds__(256) void layer1_kernel(
    const int* __restrict__ row_start, const int* __restrict__ eid,
    const int* __restrict__ etype, const float* __restrict__ W1,
    const float* __restrict__ b1, float* __restrict__ h1, int N) {
    __shared__ float W1s[NUM_RELS * 32];
    __shared__ float b1s[32];
    for (int t = threadIdx.x; t < NUM_RELS * 32; t += blockDim.x) W1s[t] = W1[t];
    if (threadIdx.x < 32) b1s[threadIdx.x] = b1[threadIdx.x];
    __syncthreads();

    int hw = (blockIdx.x * blockDim.x + threadIdx.x) >> 5;  // node id
    int o = threadIdx.x & 31;
    if (hw >= N) return;
    int start = row_start[hw], end = row_start[hw + 1];
    float acc = b1s[o];
    for (int base = start; base < end; base += 32) {
        int idx = base + o;
        int e = (idx < end) ? eid[idx] : 0;
        int r_l = (idx < end) ? etype[e] : 0;
        int cnt = min(32, end - base);
        for (int j = 0; j < cnt; ++j) {
            int r = __shfl(r_l, j, 32);
            acc += W1s[r * 32 + o];
        }
    }
    h1[(size_t)hw * 32 + o] = fmaxf(acc, 0.f);
}

// ---------------- Layer 2 + 3 fused ----------------
// Per 32-lane half-wave: one node. lane = output channel o.
// acc[o] = b2[o] + sum_e sum_i h1[src(e)][i] * W2[r_e][i][o];  h2 = relu(acc)
// out[v][o] = b3[o] + sum_i h2[i] * W3[i][o]
// LDS: W2 transposed [r][o][i] with i padded to 36 (float4 reads, <=4-way conflict), W3 [i][o].

#define W2T_PAD 36
#define W2T_FLOATS (NUM_RELS * 32 * W2T_PAD)

__global__ __launch_bounds__(1024) void layer23_kernel(
    const float* __restrict__ h1, const int* __restrict__ row_start,
    const int* __restrict__ eid, const int* __restrict__ src,
    const int* __restrict__ etype, const float* __restrict__ W2,
    const float* __restrict__ b2, const float* __restrict__ W3,
    const float* __restrict__ b3, float* __restrict__ out, int N) {
    extern __shared__ float lds[];
    float* W2T = lds;                    // [19][32][36]
    float* W3s = lds + W2T_FLOATS;       // [32][32]

    for (int t = threadIdx.x; t < NUM_RELS * 1024; t += blockDim.x) {
        int r = t >> 10, rem = t & 1023, i = rem >> 5, o = rem & 31;
        W2T[(r * 32 + o) * W2T_PAD + i] = W2[t];
    }
    for (int t = threadIdx.x; t < 1024; t += blockDim.x) W3s[t] = W3[t];
    __syncthreads();

    int hw = (blockIdx.x * blockDim.x + threadIdx.x) >> 5;  // node id
    int o = threadIdx.x & 31;
    if (hw >= N) return;
    int start = row_start[hw], end = row_start[hw + 1];

    float acc = 0.f;
    for (int base = start; base < end; base += 32) {
        int idx = base + o;
        int e = (idx < end) ? eid[idx] : 0;
        int s_l = (idx < end) ? src[e] : 0;
        int r_l = (idx < end) ? etype[e] : 0;
        int cnt = min(32, end - base);
        for (int j = 0; j < cnt; ++j) {
            int s = __shfl(s_l, j, 32);
            int r = __shfl(r_l, j, 32);
            const float4* hp = (const float4*)(h1 + (size_t)s * 32);
            const float* wp = W2T + (r * 32 + o) * W2T_PAD;
#pragma unroll
            for (int c = 0; c < 8; ++c) {
                float4 h4 = hp[c];                         // broadcast load (L1/L2)
                float4 w4 = *(const float4*)(wp + c * 4);  // LDS
                acc = fmaf(h4.x, w4.x, acc);
                acc = fmaf(h4.y, w4.y, acc);
                acc = fmaf(h4.z, w4.z, acc);
                acc = fmaf(h4.w, w4.w, acc);
            }
        }
    }
    acc += b2[o];
    float h2v = fmaxf(acc, 0.f);

    // layer 3 via cross-lane broadcast of h2
    float acc3 = b3[o];
#pragma unroll
    for (int i = 0; i < 32; ++i) {
        float hi = __shfl(h2v, i, 32);
        acc3 = fmaf(hi, W3s[i * 32 + o], acc3);
    }
    out[(size_t)hw * 32 + o] = acc3;
}

// ---------------- Host launcher ----------------

extern "C" void kernel_launch(void* const* d_in, const int* in_sizes, int n_in,
                              void* d_out, int out_size, void* d_ws, size_t ws_size,
                              hipStream_t stream) {
    const int* src   = (const int*)d_in[0];
    const int* dst   = (const int*)d_in[1];
    const int* etype = (const int*)d_in[2];
    const float* W1  = (const float*)d_in[4];
    const float* b1  = (const float*)d_in[5];
    const float* W2  = (const float*)d_in[6];
    const float* b2  = (const float*)d_in[7];
    const float* W3  = (const float*)d_in[8];
    const float* b3  = (const float*)d_in[9];
    float* out = (float*)d_out;

    int E = in_sizes[0];
    int N = out_size / 32;

    char* ws = (char*)d_ws;
    size_t off = 0;
    auto alloc = [&](size_t bytes) {
        void* p = ws + off;
        off = (off + bytes + 255) & ~(size_t)255;
        return p;
    };
    float* h1      = (float*)alloc((size_t)N * 32 * 4);
    int* count     = (int*)alloc((size_t)N * 4);
    int* row_start = (int*)alloc((size_t)(N + 1) * 4);
    int* cursor    = (int*)alloc((size_t)N * 4);
    int* bsum      = (int*)alloc(256 * 4);
    int* eid       = (int*)alloc((size_t)E * 4);

    hipMemsetAsync(count, 0, (size_t)N * 4, stream);
    hist_kernel<<<(E + 255) / 256, 256, 0, stream>>>(dst, count, E);
    int NB = (N + 2047) / 2048;
    scan1_kernel<<<NB, 256, 0, stream>>>(count, row_start, bsum, N);
    scan2_kernel<<<1, 256, 0, stream>>>(bsum, NB);
    scan3_kernel<<<(N + 1 + 255) / 256, 256, 0, stream>>>(row_start, cursor, bsum, N, E);
    scatter_kernel<<<(E + 255) / 256, 256, 0, stream>>>(dst, cursor, eid, E);
    layer1_kernel<<<(N + 7) / 8, 256, 0, stream>>>(row_start, eid, etype, W1, b1, h1, N);

    const int LDS23 = (W2T_FLOATS + 32 * 32) * 4;
    hipFuncSetAttribute(reinterpret_cast<const void*>(layer23_kernel),
                        hipFuncAttributeMaxDynamicSharedMemorySize, LDS23);
    layer23_kernel<<<(N + 31) / 32, 1024, LDS23, stream>>>(h1, row_start, eid, src, etype,
                                                           W2, b2, W3, b3, out, N);
}